// Round 16
// baseline (456.867 us; speedup 1.0000x reference)
//
#include <hip/hip_runtime.h>

#define NE 1600000
#define NN 100000
#define ETILES32 (NE / 32)        // 50000, exact (32-edge tiles)
#define NTILES ((NN + 63) / 64)   // 1563
#define CAP 48                    // bucket capacity; deg ~ Poisson(16), P(>=48) ~ 1e-9/node

typedef __attribute__((ext_vector_type(4))) float f32x4;
typedef __attribute__((ext_vector_type(8))) __bf16 bf16x8;
typedef __attribute__((ext_vector_type(8))) unsigned short u16x8;
typedef __attribute__((ext_vector_type(4))) unsigned short u16x4;

static __device__ __forceinline__ unsigned short f2bf(float f) {
    unsigned int u = __float_as_uint(f);
    u += 0x7FFFu + ((u >> 16) & 1u);   // RNE; inputs are finite
    return (unsigned short)(u >> 16);
}
static __device__ __forceinline__ float bf2f(unsigned short s) {
    return __uint_as_float(((unsigned int)s) << 16);
}
static __device__ __forceinline__ f32x4 mfma16(bf16x8 a, bf16x8 b, f32x4 c) {
    return __builtin_amdgcn_mfma_f32_16x16x32_bf16(a, b, c, 0, 0, 0);
}
// B-fragment of row-major W[K][64]: lane holds B[k][n], n=ncol, k=kbase+(l>>4)*8+j
static __device__ __forceinline__ bf16x8 load_wfrag(const float* __restrict__ W,
                                                    int kbase, int lq, int ncol) {
    u16x8 u;
#pragma unroll
    for (int j = 0; j < 8; ++j)
        u[j] = f2bf(W[(kbase + lq * 8 + j) * 64 + ncol]);
    return __builtin_bit_cast(bf16x8, u);
}
static __device__ __forceinline__ bf16x8 lds_frag(const unsigned short* p) {
    return __builtin_bit_cast(bf16x8, *(const u16x8*)p);
}

// ---------------- prep: h->bf16 (blocks 0..3124); optional bucket-index fill (fallback) ----------
__global__ __launch_bounds__(256) void k_prep(const float* __restrict__ h,
                                              unsigned short* __restrict__ hbf,
                                              const int* __restrict__ ei,
                                              int* __restrict__ cnt,
                                              int* __restrict__ eid) {
    const int bid = blockIdx.x;
    if (bid < 3125) {
        const size_t i = ((size_t)bid * 256 + threadIdx.x) * 8;
        const f32x4 a = __builtin_nontemporal_load((const f32x4*)(h + i));
        const f32x4 b = __builtin_nontemporal_load((const f32x4*)(h + i + 4));
        u16x8 u;
#pragma unroll
        for (int j = 0; j < 4; ++j) { u[j] = f2bf(a[j]); u[j + 4] = f2bf(b[j]); }
        *(u16x8*)(hbf + i) = u;
    } else {   // fallback path only
        int i = (bid - 3125) * 256 + threadIdx.x;
        for (; i < NE; i += 4096 * 256) {
            const int r = ei[i];
            const int pos = atomicAdd(&cnt[r], 1);
            if (pos < CAP) eid[r * CAP + pos] = i;
        }
    }
}

// -------- edge kernel: 32-edge tiles (13.95KB LDS -> target 8 blocks/CU), N-SPLIT waves ----
// Wave w owns output cols [16w,16w+16) of all 32 edges. LDS tile [32][XROW] u16:
// cols 0..63 h_row / 64..127 h_col / 128..191 e(bf16). hidden overwrites u16 cols 0..63;
// fp32 out tile aliases f32 cols 0..63 (stride 108); e-cols stay valid to tile end.
#define XROW 216   // 432B row stride

__global__ __launch_bounds__(256, 4) void gns_edge(
    const unsigned short* __restrict__ hbf, const float* __restrict__ e,
    const int* __restrict__ ei,
    const float* __restrict__ eW1, const float* __restrict__ eb1,
    const float* __restrict__ eW2, const float* __restrict__ eb2,
    float* __restrict__ ef,
    int* __restrict__ cnt, unsigned short* __restrict__ edata)
{
    __shared__ unsigned short xl[32 * XROW];  // 13824 B
    __shared__ int slotg[32];                 // bucket slot (r*CAP+pos) per tile row, -1 = drop

    const int tid = threadIdx.x;
    const int lane = tid & 63;
    const int wv = tid >> 6;          // wave 0..3 owns output cols [wv*16, wv*16+16)
    const int l15 = lane & 15;
    const int lq = lane >> 4;
    const bool scatter = (edata != nullptr);

    // weight fragments: only this wave's 16-col slice
    bf16x8 B1[6], B2[2];
#pragma unroll
    for (int kt = 0; kt < 6; ++kt)
        B1[kt] = load_wfrag(eW1, kt * 32, lq, wv * 16 + l15);
#pragma unroll
    for (int kt = 0; kt < 2; ++kt)
        B2[kt] = load_wfrag(eW2, kt * 32, lq, wv * 16 + l15);

    const float b1v = eb1[wv * 16 + l15];
    const float b2v = eb2[wv * 16 + l15];

    for (int tile = blockIdx.x; tile < ETILES32; tile += gridDim.x) {
        const int base = tile * 32;
        __syncthreads();   // protect xl/slotg from previous iteration's readers
        {   // stage x -> LDS (h parts already bf16) + bucket slot reservation
            const int sub = tid & 15;   // 16 threads per edge
            const int eg = tid >> 4;
#pragma unroll
            for (int p = 0; p < 2; ++p) {
                const int el = eg + p * 16;
                const int eidx = base + el;
                const int r = ei[eidx];
                const int c = ei[NE + eidx];
                const u16x4 ua = *(const u16x4*)(hbf + (size_t)r * 64 + sub * 4);
                const u16x4 ub = *(const u16x4*)(hbf + (size_t)c * 64 + sub * 4);
                const f32x4 ev = __builtin_nontemporal_load(
                    (const f32x4*)(e + (size_t)eidx * 64 + sub * 4));
                unsigned short* xr = xl + el * XROW;
                u16x4 ue;
#pragma unroll
                for (int j = 0; j < 4; ++j) ue[j] = f2bf(ev[j]);
                *(u16x4*)(xr + sub * 4)       = ua;
                *(u16x4*)(xr + 64 + sub * 4)  = ub;
                *(u16x4*)(xr + 128 + sub * 4) = ue;
                if (scatter && sub == 0) {
                    const int pos = atomicAdd(&cnt[r], 1);
                    slotg[el] = (pos < CAP) ? (r * CAP + pos) : -1;
                }
            }
        }
        __syncthreads();

        // stage 1: acc[m] = x[edges m*16..][:] @ eW1[:, wave cols]
        f32x4 acc[2] = {{0.f,0.f,0.f,0.f},{0.f,0.f,0.f,0.f}};
#pragma unroll
        for (int m = 0; m < 2; ++m) {
            const unsigned short* ar = xl + (m * 16 + l15) * XROW + lq * 8;
#pragma unroll
            for (int kt = 0; kt < 6; ++kt)
                acc[m] = mfma16(lds_frag(ar + kt * 32), B1[kt], acc[m]);
        }
        __syncthreads();   // all stage-1 reads done before hidden overwrites cols 0..63

        // hidden = relu(acc + b1) -> u16 cols [wv*16, wv*16+16), all 32 rows
#pragma unroll
        for (int m = 0; m < 2; ++m)
#pragma unroll
            for (int r2 = 0; r2 < 4; ++r2) {
                float v = fmaxf(acc[m][r2] + b1v, 0.f);
                xl[(m * 16 + lq * 4 + r2) * XROW + wv * 16 + l15] = f2bf(v);
            }
        __syncthreads();   // hidden complete

        // stage 2: o[m] = hidden[edges m*16..][:] @ eW2[:, wave cols]
        f32x4 o[2] = {{0.f,0.f,0.f,0.f},{0.f,0.f,0.f,0.f}};
#pragma unroll
        for (int m = 0; m < 2; ++m) {
            const unsigned short* ar = xl + (m * 16 + l15) * XROW + lq * 8;
#pragma unroll
            for (int kt = 0; kt < 2; ++kt)
                o[m] = mfma16(lds_frag(ar + kt * 32), B2[kt], o[m]);
        }
        __syncthreads();   // all stage-2 reads done before fp32 tile overwrites cols 0..127

        // out + bias + residual(e) -> fp32 tile (f32 stride 108), own cols
        float* xf = (float*)xl;
#pragma unroll
        for (int m = 0; m < 2; ++m)
#pragma unroll
            for (int r2 = 0; r2 < 4; ++r2) {
                const int el = m * 16 + lq * 4 + r2;
                const int n = wv * 16 + l15;
                xf[el * 108 + n] = o[m][r2] + b2v + bf2f(xl[el * XROW + 128 + n]);
            }
        __syncthreads();

        // coalesced f32x4 ef store + bf16 e-row scatter into buckets (both nt)
#pragma unroll
        for (int q = 0; q < 2; ++q) {
            const int c = q * 256 + tid;       // 0..511
            const int el = c >> 4, j = c & 15;
            const f32x4 v = *(const f32x4*)(xf + el * 108 + j * 4);
            __builtin_nontemporal_store(v, (f32x4*)(ef + (size_t)(base + el) * 64 + j * 4));
            if (scatter) {
                const int sg = slotg[el];
                if (sg >= 0) {
                    const u16x4 ev4 = *(const u16x4*)(xl + el * XROW + 128 + j * 4);
                    __builtin_nontemporal_store(ev4, (u16x4*)(edata + (size_t)sg * 64 + j * 4));
                }
            }
        }
    }
}

// -------- agg (fallback, R7): index-gather from e --------
__global__ __launch_bounds__(256, 6) void k_agg(
    const float* __restrict__ e, const int* __restrict__ cnt,
    const int* __restrict__ eid, unsigned short* __restrict__ aggbf)
{
    const int node = blockIdx.x * 16 + (threadIdx.x >> 4);
    const int sub = threadIdx.x & 15;
    if (node >= NN) return;

    const int dg = min(cnt[node], CAP);
    const int o0 = node * CAP;
    f32x4 ag = {0.f, 0.f, 0.f, 0.f};
    int j = 0;
    for (; j + 4 <= dg; j += 4) {
        const int i0 = eid[o0 + j], i1 = eid[o0 + j + 1];
        const int i2 = eid[o0 + j + 2], i3 = eid[o0 + j + 3];
        const f32x4 v0 = *(const f32x4*)(e + (size_t)i0 * 64 + sub * 4);
        const f32x4 v1 = *(const f32x4*)(e + (size_t)i1 * 64 + sub * 4);
        const f32x4 v2 = *(const f32x4*)(e + (size_t)i2 * 64 + sub * 4);
        const f32x4 v3 = *(const f32x4*)(e + (size_t)i3 * 64 + sub * 4);
        ag += (v0 + v1) + (v2 + v3);
    }
    for (; j < dg; ++j) {
        const int i0 = eid[o0 + j];
        ag += *(const f32x4*)(e + (size_t)i0 * 64 + sub * 4);
    }
    u16x4 ub;
#pragma unroll
    for (int k = 0; k < 4; ++k) ub[k] = f2bf(ag[k]);
    *(u16x4*)(aggbf + (size_t)node * 64 + sub * 4) = ub;
}

// -------- node MLP kernel (+fused WIDE bucket-scan agg when edata != null) ----
// Scan: 16 lanes/node read u16x8 covering TWO bucket rows per step (256B contiguous);
// lane sub owns features (sub&7)*8..+8 with row-parity sub>>3; shfl_xor(8) merges.
// LDS [64][XNROW] u16: cols 0..63 h (residual), 64..127 agg; hidden aliases 64..127.
#define XNROW 136  // 272B row stride

__global__ __launch_bounds__(256, 4) void k_nodemlp(
    const unsigned short* __restrict__ hbf, const unsigned short* __restrict__ aggbf,
    const unsigned short* __restrict__ edata, const int* __restrict__ cnt,
    const float* __restrict__ nW1, const float* __restrict__ nb1,
    const float* __restrict__ nW2, const float* __restrict__ nb2,
    float* __restrict__ hout)
{
    __shared__ unsigned short xn[64 * XNROW];  // 17408 B

    const int tid = threadIdx.x;
    const int lane = tid & 63;
    const int wv = tid >> 6;
    const int l15 = lane & 15;
    const int lq = lane >> 4;

    bf16x8 B1[4][4], B2[2][4];
#pragma unroll
    for (int kt = 0; kt < 4; ++kt)
#pragma unroll
        for (int nt = 0; nt < 4; ++nt)
            B1[kt][nt] = load_wfrag(nW1, kt * 32, lq, nt * 16 + l15);
#pragma unroll
    for (int kt = 0; kt < 2; ++kt)
#pragma unroll
        for (int nt = 0; nt < 4; ++nt)
            B2[kt][nt] = load_wfrag(nW2, kt * 32, lq, nt * 16 + l15);

    float b1v[4], b2v[4];
#pragma unroll
    for (int nt = 0; nt < 4; ++nt) {
        b1v[nt] = nb1[nt * 16 + l15];
        b2v[nt] = nb2[nt * 16 + l15];
    }

    const int base = blockIdx.x * 64;
    {   // stage [h | agg] -> LDS; agg from wide bucket scan (main) or aggbf (fallback)
        const int sub = tid & 15;
        const int ng = tid >> 4;
#pragma unroll
        for (int p = 0; p < 4; ++p) {
            const int nl = ng + p * 16;
            const int node = base + nl;
            u16x4 ua = {0, 0, 0, 0};
            unsigned short* xr = xn + nl * XNROW;
            if (node < NN)
                ua = *(const u16x4*)(hbf + (size_t)node * 64 + sub * 4);
            *(u16x4*)(xr + sub * 4) = ua;

            if (edata != nullptr) {
                const int dg = (node < NN) ? min(cnt[node], CAP) : 0;
                const unsigned short* bp = edata + (size_t)node * CAP * 64;
                const int ro = sub >> 3;            // row parity
                const int fo = (sub & 7) * 8;       // feature offset (u16)
                float ag8[8] = {0.f,0.f,0.f,0.f,0.f,0.f,0.f,0.f};
                int j = 0;
                for (; j + 4 <= dg; j += 4) {       // 4 rows in flight (512B/group)
                    const u16x8 a = __builtin_nontemporal_load(
                        (const u16x8*)(bp + (j + ro) * 64 + fo));
                    const u16x8 b = __builtin_nontemporal_load(
                        (const u16x8*)(bp + (j + 2 + ro) * 64 + fo));
#pragma unroll
                    for (int k = 0; k < 8; ++k) ag8[k] += bf2f(a[k]) + bf2f(b[k]);
                }
                for (; j + 2 <= dg; j += 2) {       // 2 rows
                    const u16x8 a = __builtin_nontemporal_load(
                        (const u16x8*)(bp + (j + ro) * 64 + fo));
#pragma unroll
                    for (int k = 0; k < 8; ++k) ag8[k] += bf2f(a[k]);
                }
                if (j < dg && sub < 8) {            // odd tail row: lanes 0..7 cover it
                    const u16x8 a = __builtin_nontemporal_load(
                        (const u16x8*)(bp + j * 64 + fo));
#pragma unroll
                    for (int k = 0; k < 8; ++k) ag8[k] += bf2f(a[k]);
                }
                // merge row-parity partials across sub^8 (uniform for the 16-lane group)
#pragma unroll
                for (int k = 0; k < 8; ++k) ag8[k] += __shfl_xor(ag8[k], 8);
                if (sub < 8) {
                    u16x8 u;
#pragma unroll
                    for (int k = 0; k < 8; ++k) u[k] = f2bf(ag8[k]);
                    *(u16x8*)(xr + 64 + sub * 8) = u;
                }
            } else {
                u16x4 ub = {0, 0, 0, 0};
                if (node < NN)
                    ub = *(const u16x4*)(aggbf + (size_t)node * 64 + sub * 4);
                *(u16x4*)(xr + 64 + sub * 4) = ub;
            }
        }
    }
    __syncthreads();

    f32x4 acc[4] = {{0.f,0.f,0.f,0.f},{0.f,0.f,0.f,0.f},{0.f,0.f,0.f,0.f},{0.f,0.f,0.f,0.f}};
    const int arow = wv * 16 + l15;
#pragma unroll
    for (int kt = 0; kt < 4; ++kt) {
        bf16x8 a = lds_frag(xn + arow * XNROW + kt * 32 + lq * 8);
#pragma unroll
        for (int nt = 0; nt < 4; ++nt) acc[nt] = mfma16(a, B1[kt][nt], acc[nt]);
    }
    // hidden -> cols 64..127 of own wave's rows (h kept in 0..63 for residual)
#pragma unroll
    for (int nt = 0; nt < 4; ++nt)
#pragma unroll
        for (int r2 = 0; r2 < 4; ++r2) {
            float v = fmaxf(acc[nt][r2] + b1v[nt], 0.f);
            xn[(wv * 16 + lq * 4 + r2) * XNROW + 64 + nt * 16 + l15] = f2bf(v);
        }

    f32x4 o[4] = {{0.f,0.f,0.f,0.f},{0.f,0.f,0.f,0.f},{0.f,0.f,0.f,0.f},{0.f,0.f,0.f,0.f}};
#pragma unroll
    for (int kt = 0; kt < 2; ++kt) {
        bf16x8 a = lds_frag(xn + arow * XNROW + 64 + kt * 32 + lq * 8);
#pragma unroll
        for (int nt = 0; nt < 4; ++nt) o[nt] = mfma16(a, B2[kt][nt], o[nt]);
    }
#pragma unroll
    for (int nt = 0; nt < 4; ++nt)
#pragma unroll
        for (int r2 = 0; r2 < 4; ++r2) {
            const int nl = wv * 16 + lq * 4 + r2;
            const int node = base + nl;
            const int n = nt * 16 + l15;
            float v = o[nt][r2] + b2v[nt] + bf2f(xn[nl * XNROW + n]);
            if (node < NN) hout[(size_t)node * 64 + n] = v;
        }
}

extern "C" void kernel_launch(void* const* d_in, const int* in_sizes, int n_in,
                              void* d_out, int out_size, void* d_ws, size_t ws_size,
                              hipStream_t stream) {
    const float* h   = (const float*)d_in[0];
    const float* e   = (const float*)d_in[1];
    const int*   ei  = (const int*)d_in[2];
    const float* eW1 = (const float*)d_in[3];
    const float* eb1 = (const float*)d_in[4];
    const float* eW2 = (const float*)d_in[5];
    const float* eb2 = (const float*)d_in[6];
    // d_in[7..10] = gate params: unused in outputs, skipped entirely
    const float* nW1 = (const float*)d_in[11];
    const float* nb1 = (const float*)d_in[12];
    const float* nW2 = (const float*)d_in[13];
    const float* nb2 = (const float*)d_in[14];

    float* out = (float*)d_out;               // [h_out (NN*64) | edge_feat (NE*64)]

    // workspace layout (16B-aligned): hbf | aggbf | cnt | {edata (main) or eid (fallback)}
    unsigned short* hbf   = (unsigned short*)d_ws;          // NN*64 u16 = 12.8 MB
    unsigned short* aggbf = hbf + (size_t)NN * 64;          // NN*64 u16 = 12.8 MB (fallback only)
    int* cnt = (int*)(aggbf + (size_t)NN * 64);             // NN ints
    void* tail = (void*)(cnt + ((NN + 3) & ~3));

    const size_t fixed = (size_t)((char*)tail - (char*)d_ws);
    const size_t need_edata = (size_t)NN * CAP * 64 * 2;    // 614.4 MB

    hipMemsetAsync(cnt, 0, (size_t)NN * sizeof(int), stream);

    if (ws_size >= fixed + need_edata) {
        // main path: edge kernel scatters bf16 e-rows into buckets; nodemlp scans them
        unsigned short* edata = (unsigned short*)tail;
        k_prep<<<3125, 256, 0, stream>>>(h, hbf, ei, cnt, nullptr);        // h2bf only
        gns_edge<<<2048, 256, 0, stream>>>(hbf, e, ei, eW1, eb1, eW2, eb2,
                                           out + (size_t)NN * 64, cnt, edata);
        k_nodemlp<<<NTILES, 256, 0, stream>>>(hbf, nullptr, edata, cnt,
                                              nW1, nb1, nW2, nb2, out);
    } else {
        // fallback (R7): index buckets in prep; random-gather agg
        int* eid = (int*)tail;                               // NN*CAP ints = 19.2 MB
        k_prep<<<7221, 256, 0, stream>>>(h, hbf, ei, cnt, eid);
        gns_edge<<<2048, 256, 0, stream>>>(hbf, e, ei, eW1, eb1, eW2, eb2,
                                           out + (size_t)NN * 64, nullptr, nullptr);
        k_agg<<<6250, 256, 0, stream>>>(e, cnt, eid, aggbf);
        k_nodemlp<<<NTILES, 256, 0, stream>>>(hbf, aggbf, nullptr, nullptr,
                                              nW1, nb1, nW2, nb2, out);
    }
}

// Round 17
// 445.038 us; speedup vs baseline: 1.0266x; 1.0266x over previous
//
#include <hip/hip_runtime.h>

#define NE 1600000
#define NN 100000
#define ETILES (NE / 64)          // 25000, exact
#define NTILES ((NN + 63) / 64)   // 1563
#define CAP 48                    // bucket capacity; deg ~ Poisson(16), P(>=48) ~ 1e-9/node

typedef __attribute__((ext_vector_type(4))) float f32x4;
typedef __attribute__((ext_vector_type(8))) __bf16 bf16x8;
typedef __attribute__((ext_vector_type(8))) unsigned short u16x8;
typedef __attribute__((ext_vector_type(4))) unsigned short u16x4;

static __device__ __forceinline__ unsigned short f2bf(float f) {
    unsigned int u = __float_as_uint(f);
    u += 0x7FFFu + ((u >> 16) & 1u);   // RNE; inputs are finite
    return (unsigned short)(u >> 16);
}
static __device__ __forceinline__ float bf2f(unsigned short s) {
    return __uint_as_float(((unsigned int)s) << 16);
}
static __device__ __forceinline__ f32x4 mfma16(bf16x8 a, bf16x8 b, f32x4 c) {
    return __builtin_amdgcn_mfma_f32_16x16x32_bf16(a, b, c, 0, 0, 0);
}
// B-fragment of row-major W[K][64]: lane holds B[k][n], n=ncol, k=kbase+(l>>4)*8+j
static __device__ __forceinline__ bf16x8 load_wfrag(const float* __restrict__ W,
                                                    int kbase, int lq, int ncol) {
    u16x8 u;
#pragma unroll
    for (int j = 0; j < 8; ++j)
        u[j] = f2bf(W[(kbase + lq * 8 + j) * 64 + ncol]);
    return __builtin_bit_cast(bf16x8, u);
}
static __device__ __forceinline__ bf16x8 lds_frag(const unsigned short* p) {
    return __builtin_bit_cast(bf16x8, *(const u16x8*)p);
}

// ---------------- prep: h->bf16 (blocks 0..3124); optional bucket-index fill (fallback) ----------
__global__ __launch_bounds__(256) void k_prep(const float* __restrict__ h,
                                              unsigned short* __restrict__ hbf,
                                              const int* __restrict__ ei,
                                              int* __restrict__ cnt,
                                              int* __restrict__ eid) {
    const int bid = blockIdx.x;
    if (bid < 3125) {
        const size_t i = ((size_t)bid * 256 + threadIdx.x) * 8;
        const f32x4 a = __builtin_nontemporal_load((const f32x4*)(h + i));
        const f32x4 b = __builtin_nontemporal_load((const f32x4*)(h + i + 4));
        u16x8 u;
#pragma unroll
        for (int j = 0; j < 4; ++j) { u[j] = f2bf(a[j]); u[j + 4] = f2bf(b[j]); }
        *(u16x8*)(hbf + i) = u;
    } else {   // fallback path only
        int i = (bid - 3125) * 256 + threadIdx.x;
        for (; i < NE; i += 4096 * 256) {
            const int r = ei[i];
            const int pos = atomicAdd(&cnt[r], 1);
            if (pos < CAP) eid[r * CAP + pos] = i;
        }
    }
}

// -------- edge kernel (best measured, R13): N-SPLIT waves (wave w owns cols [16w,16w+16)) ------
// Single LDS tile [64][XROW] u16: cols 0..63 h_row / 64..127 h_col / 128..191 e(bf16).
// hidden overwrites u16 cols 0..63 (after barrier); fp32 out tile aliases f32 cols 0..63
// (stride 108, u16 cols 0..127); e-cols 128..191 stay valid to the end of the tile.
#define XROW 216   // 432B row stride

__global__ __launch_bounds__(256, 4) void gns_edge(
    const unsigned short* __restrict__ hbf, const float* __restrict__ e,
    const int* __restrict__ ei,
    const float* __restrict__ eW1, const float* __restrict__ eb1,
    const float* __restrict__ eW2, const float* __restrict__ eb2,
    float* __restrict__ ef,
    int* __restrict__ cnt, unsigned short* __restrict__ edata)
{
    __shared__ unsigned short xl[64 * XROW];  // 27648 B
    __shared__ int slotg[64];                 // bucket slot (r*CAP+pos) per tile row, -1 = drop

    const int tid = threadIdx.x;
    const int lane = tid & 63;
    const int wv = tid >> 6;          // wave 0..3 owns output cols [wv*16, wv*16+16)
    const int l15 = lane & 15;
    const int lq = lane >> 4;
    const bool scatter = (edata != nullptr);

    // weight fragments: only this wave's 16-col slice
    bf16x8 B1[6], B2[2];
#pragma unroll
    for (int kt = 0; kt < 6; ++kt)
        B1[kt] = load_wfrag(eW1, kt * 32, lq, wv * 16 + l15);
#pragma unroll
    for (int kt = 0; kt < 2; ++kt)
        B2[kt] = load_wfrag(eW2, kt * 32, lq, wv * 16 + l15);

    const float b1v = eb1[wv * 16 + l15];
    const float b2v = eb2[wv * 16 + l15];

    for (int tile = blockIdx.x; tile < ETILES; tile += gridDim.x) {
        const int base = tile * 64;
        __syncthreads();   // protect xl/slotg from previous iteration's readers
        {   // stage x -> LDS (h parts already bf16) + bucket slot reservation
            const int sub = tid & 15;   // 16 threads per edge
            const int eg = tid >> 4;
#pragma unroll
            for (int p = 0; p < 4; ++p) {
                const int el = eg + p * 16;
                const int eidx = base + el;
                const int r = ei[eidx];
                const int c = ei[NE + eidx];
                const u16x4 ua = *(const u16x4*)(hbf + (size_t)r * 64 + sub * 4);
                const u16x4 ub = *(const u16x4*)(hbf + (size_t)c * 64 + sub * 4);
                const f32x4 ev = __builtin_nontemporal_load(
                    (const f32x4*)(e + (size_t)eidx * 64 + sub * 4));
                unsigned short* xr = xl + el * XROW;
                u16x4 ue;
#pragma unroll
                for (int j = 0; j < 4; ++j) ue[j] = f2bf(ev[j]);
                *(u16x4*)(xr + sub * 4)       = ua;
                *(u16x4*)(xr + 64 + sub * 4)  = ub;
                *(u16x4*)(xr + 128 + sub * 4) = ue;
                if (scatter && sub == 0) {
                    const int pos = atomicAdd(&cnt[r], 1);
                    slotg[el] = (pos < CAP) ? (r * CAP + pos) : -1;
                }
            }
        }
        __syncthreads();

        // stage 1: acc[m] = x[edges m*16..][:] @ eW1[:, wave cols]
        f32x4 acc[4] = {{0.f,0.f,0.f,0.f},{0.f,0.f,0.f,0.f},{0.f,0.f,0.f,0.f},{0.f,0.f,0.f,0.f}};
#pragma unroll
        for (int m = 0; m < 4; ++m) {
            const unsigned short* ar = xl + (m * 16 + l15) * XROW + lq * 8;
#pragma unroll
            for (int kt = 0; kt < 6; ++kt)
                acc[m] = mfma16(lds_frag(ar + kt * 32), B1[kt], acc[m]);
        }
        __syncthreads();   // all stage-1 reads done before hidden overwrites cols 0..63

        // hidden = relu(acc + b1) -> u16 cols [wv*16, wv*16+16), all 64 rows
#pragma unroll
        for (int m = 0; m < 4; ++m)
#pragma unroll
            for (int r2 = 0; r2 < 4; ++r2) {
                float v = fmaxf(acc[m][r2] + b1v, 0.f);
                xl[(m * 16 + lq * 4 + r2) * XROW + wv * 16 + l15] = f2bf(v);
            }
        __syncthreads();   // hidden complete

        // stage 2: o[m] = hidden[edges m*16..][:] @ eW2[:, wave cols]
        f32x4 o[4] = {{0.f,0.f,0.f,0.f},{0.f,0.f,0.f,0.f},{0.f,0.f,0.f,0.f},{0.f,0.f,0.f,0.f}};
#pragma unroll
        for (int m = 0; m < 4; ++m) {
            const unsigned short* ar = xl + (m * 16 + l15) * XROW + lq * 8;
#pragma unroll
            for (int kt = 0; kt < 2; ++kt)
                o[m] = mfma16(lds_frag(ar + kt * 32), B2[kt], o[m]);
        }
        __syncthreads();   // all stage-2 reads done before fp32 tile overwrites cols 0..127

        // out + bias + residual(e) -> fp32 tile (f32 stride 108), own cols
        float* xf = (float*)xl;
#pragma unroll
        for (int m = 0; m < 4; ++m)
#pragma unroll
            for (int r2 = 0; r2 < 4; ++r2) {
                const int el = m * 16 + lq * 4 + r2;
                const int n = wv * 16 + l15;
                xf[el * 108 + n] = o[m][r2] + b2v + bf2f(xl[el * XROW + 128 + n]);
            }
        __syncthreads();

        // coalesced f32x4 ef store + bf16 e-row scatter into buckets (both nt)
#pragma unroll
        for (int q = 0; q < 4; ++q) {
            const int c = q * 256 + tid;       // 0..1023
            const int el = c >> 4, j = c & 15;
            const f32x4 v = *(const f32x4*)(xf + el * 108 + j * 4);
            __builtin_nontemporal_store(v, (f32x4*)(ef + (size_t)(base + el) * 64 + j * 4));
            if (scatter) {
                const int sg = slotg[el];
                if (sg >= 0) {
                    const u16x4 ev4 = *(const u16x4*)(xl + el * XROW + 128 + j * 4);
                    __builtin_nontemporal_store(ev4, (u16x4*)(edata + (size_t)sg * 64 + j * 4));
                }
            }
        }
    }
}

// -------- agg (fallback, R7): index-gather from e --------
__global__ __launch_bounds__(256, 6) void k_agg(
    const float* __restrict__ e, const int* __restrict__ cnt,
    const int* __restrict__ eid, unsigned short* __restrict__ aggbf)
{
    const int node = blockIdx.x * 16 + (threadIdx.x >> 4);
    const int sub = threadIdx.x & 15;
    if (node >= NN) return;

    const int dg = min(cnt[node], CAP);
    const int o0 = node * CAP;
    f32x4 ag = {0.f, 0.f, 0.f, 0.f};
    int j = 0;
    for (; j + 4 <= dg; j += 4) {
        const int i0 = eid[o0 + j], i1 = eid[o0 + j + 1];
        const int i2 = eid[o0 + j + 2], i3 = eid[o0 + j + 3];
        const f32x4 v0 = *(const f32x4*)(e + (size_t)i0 * 64 + sub * 4);
        const f32x4 v1 = *(const f32x4*)(e + (size_t)i1 * 64 + sub * 4);
        const f32x4 v2 = *(const f32x4*)(e + (size_t)i2 * 64 + sub * 4);
        const f32x4 v3 = *(const f32x4*)(e + (size_t)i3 * 64 + sub * 4);
        ag += (v0 + v1) + (v2 + v3);
    }
    for (; j < dg; ++j) {
        const int i0 = eid[o0 + j];
        ag += *(const f32x4*)(e + (size_t)i0 * 64 + sub * 4);
    }
    u16x4 ub;
#pragma unroll
    for (int k = 0; k < 4; ++k) ub[k] = f2bf(ag[k]);
    *(u16x4*)(aggbf + (size_t)node * 64 + sub * 4) = ub;
}

// -------- node MLP kernel (+fused bucket-scan agg when edata != null) ----
// LDS [64][XNROW] u16: cols 0..63 h (residual), 64..127 agg; hidden aliases 64..127.
#define XNROW 136  // 272B row stride

__global__ __launch_bounds__(256, 4) void k_nodemlp(
    const unsigned short* __restrict__ hbf, const unsigned short* __restrict__ aggbf,
    const unsigned short* __restrict__ edata, const int* __restrict__ cnt,
    const float* __restrict__ nW1, const float* __restrict__ nb1,
    const float* __restrict__ nW2, const float* __restrict__ nb2,
    float* __restrict__ hout)
{
    __shared__ unsigned short xn[64 * XNROW];  // 17408 B

    const int tid = threadIdx.x;
    const int lane = tid & 63;
    const int wv = tid >> 6;
    const int l15 = lane & 15;
    const int lq = lane >> 4;

    bf16x8 B1[4][4], B2[2][4];
#pragma unroll
    for (int kt = 0; kt < 4; ++kt)
#pragma unroll
        for (int nt = 0; nt < 4; ++nt)
            B1[kt][nt] = load_wfrag(nW1, kt * 32, lq, nt * 16 + l15);
#pragma unroll
    for (int kt = 0; kt < 2; ++kt)
#pragma unroll
        for (int nt = 0; nt < 4; ++nt)
            B2[kt][nt] = load_wfrag(nW2, kt * 32, lq, nt * 16 + l15);

    float b1v[4], b2v[4];
#pragma unroll
    for (int nt = 0; nt < 4; ++nt) {
        b1v[nt] = nb1[nt * 16 + l15];
        b2v[nt] = nb2[nt * 16 + l15];
    }

    const int base = blockIdx.x * 64;
    {   // stage [h | agg] -> LDS; agg from sequential bucket scan (main) or aggbf (fallback)
        const int sub = tid & 15;
        const int ng = tid >> 4;
#pragma unroll
        for (int p = 0; p < 4; ++p) {
            const int nl = ng + p * 16;
            const int node = base + nl;
            u16x4 ua = {0, 0, 0, 0};
            f32x4 ag = {0.f, 0.f, 0.f, 0.f};
            if (node < NN) {
                ua = *(const u16x4*)(hbf + (size_t)node * 64 + sub * 4);
                if (edata != nullptr) {
                    const int dg = min(cnt[node], CAP);
                    const unsigned short* bp = edata + (size_t)node * CAP * 64;
                    int j = 0;
                    for (; j + 4 <= dg; j += 4) {
                        u16x4 a = __builtin_nontemporal_load((const u16x4*)(bp + (j + 0) * 64 + sub * 4));
                        u16x4 b = __builtin_nontemporal_load((const u16x4*)(bp + (j + 1) * 64 + sub * 4));
                        u16x4 c = __builtin_nontemporal_load((const u16x4*)(bp + (j + 2) * 64 + sub * 4));
                        u16x4 d = __builtin_nontemporal_load((const u16x4*)(bp + (j + 3) * 64 + sub * 4));
#pragma unroll
                        for (int k = 0; k < 4; ++k)
                            ag[k] += (bf2f(a[k]) + bf2f(b[k])) + (bf2f(c[k]) + bf2f(d[k]));
                    }
                    for (; j < dg; ++j) {
                        u16x4 a = __builtin_nontemporal_load((const u16x4*)(bp + j * 64 + sub * 4));
#pragma unroll
                        for (int k = 0; k < 4; ++k) ag[k] += bf2f(a[k]);
                    }
                } else {
                    const u16x4 ub = *(const u16x4*)(aggbf + (size_t)node * 64 + sub * 4);
#pragma unroll
                    for (int k = 0; k < 4; ++k) ag[k] = bf2f(ub[k]);
                }
            }
            unsigned short* xr = xn + nl * XNROW;
            u16x4 ub;
#pragma unroll
            for (int j = 0; j < 4; ++j) ub[j] = f2bf(ag[j]);
            *(u16x4*)(xr + sub * 4)      = ua;
            *(u16x4*)(xr + 64 + sub * 4) = ub;
        }
    }
    __syncthreads();

    f32x4 acc[4] = {{0.f,0.f,0.f,0.f},{0.f,0.f,0.f,0.f},{0.f,0.f,0.f,0.f},{0.f,0.f,0.f,0.f}};
    const int arow = wv * 16 + l15;
#pragma unroll
    for (int kt = 0; kt < 4; ++kt) {
        bf16x8 a = lds_frag(xn + arow * XNROW + kt * 32 + lq * 8);
#pragma unroll
        for (int nt = 0; nt < 4; ++nt) acc[nt] = mfma16(a, B1[kt][nt], acc[nt]);
    }
    // hidden -> cols 64..127 of own wave's rows (h kept in 0..63 for residual)
#pragma unroll
    for (int nt = 0; nt < 4; ++nt)
#pragma unroll
        for (int r2 = 0; r2 < 4; ++r2) {
            float v = fmaxf(acc[nt][r2] + b1v[nt], 0.f);
            xn[(wv * 16 + lq * 4 + r2) * XNROW + 64 + nt * 16 + l15] = f2bf(v);
        }

    f32x4 o[4] = {{0.f,0.f,0.f,0.f},{0.f,0.f,0.f,0.f},{0.f,0.f,0.f,0.f},{0.f,0.f,0.f,0.f}};
#pragma unroll
    for (int kt = 0; kt < 2; ++kt) {
        bf16x8 a = lds_frag(xn + arow * XNROW + 64 + kt * 32 + lq * 8);
#pragma unroll
        for (int nt = 0; nt < 4; ++nt) o[nt] = mfma16(a, B2[kt][nt], o[nt]);
    }
#pragma unroll
    for (int nt = 0; nt < 4; ++nt)
#pragma unroll
        for (int r2 = 0; r2 < 4; ++r2) {
            const int nl = wv * 16 + lq * 4 + r2;
            const int node = base + nl;
            const int n = nt * 16 + l15;
            float v = o[nt][r2] + b2v[nt] + bf2f(xn[nl * XNROW + n]);
            if (node < NN) hout[(size_t)node * 64 + n] = v;
        }
}

extern "C" void kernel_launch(void* const* d_in, const int* in_sizes, int n_in,
                              void* d_out, int out_size, void* d_ws, size_t ws_size,
                              hipStream_t stream) {
    const float* h   = (const float*)d_in[0];
    const float* e   = (const float*)d_in[1];
    const int*   ei  = (const int*)d_in[2];
    const float* eW1 = (const float*)d_in[3];
    const float* eb1 = (const float*)d_in[4];
    const float* eW2 = (const float*)d_in[5];
    const float* eb2 = (const float*)d_in[6];
    // d_in[7..10] = gate params: unused in outputs, skipped entirely
    const float* nW1 = (const float*)d_in[11];
    const float* nb1 = (const float*)d_in[12];
    const float* nW2 = (const float*)d_in[13];
    const float* nb2 = (const float*)d_in[14];

    float* out = (float*)d_out;               // [h_out (NN*64) | edge_feat (NE*64)]

    // workspace layout (16B-aligned): hbf | aggbf | cnt | {edata (main) or eid (fallback)}
    unsigned short* hbf   = (unsigned short*)d_ws;          // NN*64 u16 = 12.8 MB
    unsigned short* aggbf = hbf + (size_t)NN * 64;          // NN*64 u16 = 12.8 MB (fallback only)
    int* cnt = (int*)(aggbf + (size_t)NN * 64);             // NN ints
    void* tail = (void*)(cnt + ((NN + 3) & ~3));

    const size_t fixed = (size_t)((char*)tail - (char*)d_ws);
    const size_t need_edata = (size_t)NN * CAP * 64 * 2;    // 614.4 MB

    hipMemsetAsync(cnt, 0, (size_t)NN * sizeof(int), stream);

    if (ws_size >= fixed + need_edata) {
        // main path: edge kernel scatters bf16 e-rows into buckets; nodemlp scans them
        unsigned short* edata = (unsigned short*)tail;
        k_prep<<<3125, 256, 0, stream>>>(h, hbf, ei, cnt, nullptr);        // h2bf only
        gns_edge<<<2048, 256, 0, stream>>>(hbf, e, ei, eW1, eb1, eW2, eb2,
                                           out + (size_t)NN * 64, cnt, edata);
        k_nodemlp<<<NTILES, 256, 0, stream>>>(hbf, nullptr, edata, cnt,
                                              nW1, nb1, nW2, nb2, out);
    } else {
        // fallback (R7): index buckets in prep; random-gather agg
        int* eid = (int*)tail;                               // NN*CAP ints = 19.2 MB
        k_prep<<<7221, 256, 0, stream>>>(h, hbf, ei, cnt, eid);
        gns_edge<<<2048, 256, 0, stream>>>(hbf, e, ei, eW1, eb1, eW2, eb2,
                                           out + (size_t)NN * 64, nullptr, nullptr);
        k_agg<<<6250, 256, 0, stream>>>(e, cnt, eid, aggbf);
        k_nodemlp<<<NTILES, 256, 0, stream>>>(hbf, aggbf, nullptr, nullptr,
                                              nW1, nb1, nW2, nb2, out);
    }
}